// Round 7
// baseline (10997.723 us; speedup 1.0000x reference)
//
#include <hip/hip_runtime.h>
#include <cmath>

#define L_SEQ 4096
#define DIM_  2048
#define QKV3  6144
#define HD    512
#define NH_   4
#define CHUNK_ 1024
#define NC_   4
#define NAH_  16
#define AHD   128
#define WIN   1024

static constexpr float BASE_LR_INV_F = -4.6001660298893f; // 0.01 + log(-expm1(-0.01))

__device__ __forceinline__ float sigmoidf_(float x){ return 1.0f/(1.0f+expf(-x)); }
__device__ __forceinline__ float siluf_(float x){ return x/(1.0f+expf(-x)); }
__device__ __forceinline__ float softplusf_(float x){ return (x>20.f)? x : log1pf(expf(x)); }

__device__ __forceinline__ float bf2f(unsigned short b){
    union { unsigned int u; float f; } x; x.u = ((unsigned int)b) << 16; return x.f;
}
__device__ __forceinline__ unsigned short f2bf(float f){
    union { float f; unsigned int u; } x; x.f = f;
    unsigned int r = x.u + 0x7fff + ((x.u >> 16) & 1);   // RNE
    return (unsigned short)(r >> 16);
}

__device__ __forceinline__ float waveReduceSum(float v){
    #pragma unroll
    for (int s=32; s; s>>=1) v += __shfl_xor(v, s, 64);
    return v;
}

typedef __attribute__((ext_vector_type(8))) short  bfrag;   // 8 bf16 = 4 VGPR
typedef __attribute__((ext_vector_type(4))) float  f32x4;   // 4 fp32

// ================= bf16 MFMA GEMM (fp32 in, fp32/bf16 out) =================
// C[M,N] = opA(A)*opB(B). OPA=0: A [M,K]; OPA=1: A stored [K,M].
// OPB=0: B [K,N] (optional per-k scale); OPB=1: B stored [N,K].
// M,N mult of 64; K mult of 32. 64x64 tile, 4 waves, each a 32x32 quadrant.
template<bool C16_>
__device__ __forceinline__ void store_frag(void* Cv, long base, int ldc, int gr0, int gc, f32x4 v){
    #pragma unroll
    for (int r = 0; r < 4; ++r) {
        float f = v[r];
        if (C16_) ((unsigned short*)Cv)[base + (long)(gr0+r)*ldc + gc] = f2bf(f);
        else      ((float*)Cv)[base + (long)(gr0+r)*ldc + gc] = f;
    }
}

template<int OPA, int OPB, bool KSCALE, bool C16>
__launch_bounds__(256)
__global__ void gemm_mfma(const float* __restrict__ A, const float* __restrict__ B,
                          void* __restrict__ Cv, int M, int N, int K, int ldc,
                          long sA, long sB, long sC,
                          const float* __restrict__ kscale, long sKs)
{
    const int bz = blockIdx.z;
    A += (long)bz * sA;  B += (long)bz * sB;
    const float* sc = KSCALE ? (kscale + (long)bz * sKs) : nullptr;

    const int row0 = blockIdx.y * 64;
    const int col0 = blockIdx.x * 64;
    const int tid = threadIdx.x, lane = tid & 63, w = tid >> 6;
    const int wr = (w >> 1) * 32, wc = (w & 1) * 32;
    const int lda = OPA ? M : K;
    const int ldb = OPB ? K : N;

    __shared__ __align__(16) short As[64][40];   // [row][k] bf16, +8 pad
    __shared__ __align__(16) short Bs[64][40];   // [col][k] bf16 (opB(B)^T)

    f32x4 acc00{0.f,0.f,0.f,0.f}, acc01{0.f,0.f,0.f,0.f};
    f32x4 acc10{0.f,0.f,0.f,0.f}, acc11{0.f,0.f,0.f,0.f};

    for (int k0 = 0; k0 < K; k0 += 32) {
        // ---- stage A tile -> As[r][k] = opA(A)[row0+r][k0+k]
        if (OPA == 0) {
            int r = tid >> 2, kk = (tid & 3) * 8;
            const float* src = A + (long)(row0 + r)*lda + k0 + kk;
            float4 v0 = *(const float4*)src, v1 = *(const float4*)(src + 4);
            unsigned int p0 = (unsigned)f2bf(v0.x) | ((unsigned)f2bf(v0.y) << 16);
            unsigned int p1 = (unsigned)f2bf(v0.z) | ((unsigned)f2bf(v0.w) << 16);
            unsigned int p2 = (unsigned)f2bf(v1.x) | ((unsigned)f2bf(v1.y) << 16);
            unsigned int p3 = (unsigned)f2bf(v1.z) | ((unsigned)f2bf(v1.w) << 16);
            *(uint4*)&As[r][kk] = make_uint4(p0, p1, p2, p3);
        } else {
            int kk = tid >> 3, r0 = (tid & 7) * 8;
            const float* src = A + (long)(k0 + kk)*lda + row0 + r0;
            float4 v0 = *(const float4*)src, v1 = *(const float4*)(src + 4);
            float vv[8] = {v0.x,v0.y,v0.z,v0.w,v1.x,v1.y,v1.z,v1.w};
            #pragma unroll
            for (int j = 0; j < 8; ++j) As[r0+j][kk] = (short)f2bf(vv[j]);
        }
        // ---- stage B tile -> Bs[c][k] = opB(B)[k0+k][col0+c]
        if (OPB == 1) {
            int c = tid >> 2, kk = (tid & 3) * 8;
            const float* src = B + (long)(col0 + c)*ldb + k0 + kk;
            float4 v0 = *(const float4*)src, v1 = *(const float4*)(src + 4);
            unsigned int p0 = (unsigned)f2bf(v0.x) | ((unsigned)f2bf(v0.y) << 16);
            unsigned int p1 = (unsigned)f2bf(v0.z) | ((unsigned)f2bf(v0.w) << 16);
            unsigned int p2 = (unsigned)f2bf(v1.x) | ((unsigned)f2bf(v1.y) << 16);
            unsigned int p3 = (unsigned)f2bf(v1.z) | ((unsigned)f2bf(v1.w) << 16);
            *(uint4*)&Bs[c][kk] = make_uint4(p0, p1, p2, p3);
        } else {
            int kk = tid >> 3, c0 = (tid & 7) * 8;
            const float* src = B + (long)(k0 + kk)*ldb + col0 + c0;
            float4 v0 = *(const float4*)src, v1 = *(const float4*)(src + 4);
            float vv[8] = {v0.x,v0.y,v0.z,v0.w,v1.x,v1.y,v1.z,v1.w};
            if (KSCALE) {
                float s = sc[k0 + kk];
                #pragma unroll
                for (int j = 0; j < 8; ++j) vv[j] *= s;
            }
            #pragma unroll
            for (int j = 0; j < 8; ++j) Bs[c0+j][kk] = (short)f2bf(vv[j]);
        }
        __syncthreads();
        // ---- fragments + 4 MFMAs (wave quadrant 32x32)
        {
            const int fr = lane & 15, fk = (lane >> 4) * 8;
            bfrag a0 = *(const bfrag*)&As[wr      + fr][fk];
            bfrag a1 = *(const bfrag*)&As[wr + 16 + fr][fk];
            bfrag b0 = *(const bfrag*)&Bs[wc      + fr][fk];
            bfrag b1 = *(const bfrag*)&Bs[wc + 16 + fr][fk];
            acc00 = __builtin_amdgcn_mfma_f32_16x16x32_bf16(a0, b0, acc00, 0, 0, 0);
            acc01 = __builtin_amdgcn_mfma_f32_16x16x32_bf16(a0, b1, acc01, 0, 0, 0);
            acc10 = __builtin_amdgcn_mfma_f32_16x16x32_bf16(a1, b0, acc10, 0, 0, 0);
            acc11 = __builtin_amdgcn_mfma_f32_16x16x32_bf16(a1, b1, acc11, 0, 0, 0);
        }
        __syncthreads();
    }
    // ---- epilogue: C/D layout col=lane&15, row=(lane>>4)*4+reg  [m89/m91]
    const int oc = lane & 15, orr = (lane >> 4) * 4;
    const long base = (long)bz * sC;
    store_frag<C16>(Cv, base, ldc, row0 + wr      + orr, col0 + wc      + oc, acc00);
    store_frag<C16>(Cv, base, ldc, row0 + wr      + orr, col0 + wc + 16 + oc, acc01);
    store_frag<C16>(Cv, base, ldc, row0 + wr + 16 + orr, col0 + wc      + oc, acc10);
    store_frag<C16>(Cv, base, ldc, row0 + wr + 16 + orr, col0 + wc + 16 + oc, acc11);
}

template<int OPA, int OPB, bool KSCALE, bool C16>
static inline void launch_mfma(hipStream_t st, const float* A, const float* B, void* C,
                               int M, int N, int K, int ldc, long sA, long sB, long sC, int batch,
                               const float* ks = nullptr, long sKs = 0){
    dim3 g(N/64, M/64, batch);
    gemm_mfma<OPA,OPB,KSCALE,C16><<<g,256,0,st>>>(A,B,C,M,N,K,ldc,sA,sB,sC,ks,sKs);
}

// ================= fp32 tiled GEMM (Newton-Schulz only) =================
template<int OPB, bool ADDSRC>
__launch_bounds__(256)
__global__ void gemm_tile(const float* __restrict__ A, const float* __restrict__ B,
                          float* __restrict__ C, int M, int N, int K,
                          long sA, long sB, long sC,
                          const float* __restrict__ addsrc, long sAdd, float addCoef)
{
    const int bz = blockIdx.z;
    A += (long)bz * sA;  B += (long)bz * sB;  C += (long)bz * sC;
    const float* as = ADDSRC ? (addsrc + (long)bz * sAdd) : nullptr;

    const int row0 = blockIdx.y * 64;
    const int col0 = blockIdx.x * 64;
    const int tid = threadIdx.x;
    const int tx = tid & 15, ty = tid >> 4;

    __shared__ float As[16][68];
    __shared__ float Bs[16][68];

    float acc[4][4] = {};
    const int lda = K;
    const int ldb = OPB ? K : N;

    for (int k0 = 0; k0 < K; k0 += 16) {
        {   // A tile
            int linear = tid * 4;
            int r = linear >> 4, kk = linear & 15;
            float4 v = *(const float4*)(A + (long)(row0 + r)*lda + k0 + kk);
            As[kk+0][r]=v.x; As[kk+1][r]=v.y; As[kk+2][r]=v.z; As[kk+3][r]=v.w;
        }
        {   // B tile
            int linear = tid * 4;
            if (OPB == 0) {
                int kk = linear >> 6, c = linear & 63;
                float4 v = *(const float4*)(B + (long)(k0 + kk)*ldb + col0 + c);
                Bs[kk][c+0]=v.x; Bs[kk][c+1]=v.y; Bs[kk][c+2]=v.z; Bs[kk][c+3]=v.w;
            } else {
                int c = linear >> 4, kk = linear & 15;
                float4 v = *(const float4*)(B + (long)(col0 + c)*ldb + k0 + kk);
                Bs[kk+0][c]=v.x; Bs[kk+1][c]=v.y; Bs[kk+2][c]=v.z; Bs[kk+3][c]=v.w;
            }
        }
        __syncthreads();
        #pragma unroll
        for (int kk = 0; kk < 16; ++kk) {
            float a[4], b[4];
            #pragma unroll
            for (int i=0;i<4;++i) a[i] = As[kk][ty*4+i];
            #pragma unroll
            for (int j=0;j<4;++j) b[j] = Bs[kk][tx*4+j];
            #pragma unroll
            for (int i=0;i<4;++i)
                #pragma unroll
                for (int j=0;j<4;++j) acc[i][j] += a[i]*b[j];
        }
        __syncthreads();
    }
    #pragma unroll
    for (int i=0;i<4;++i) {
        int r = row0 + ty*4 + i;
        #pragma unroll
        for (int j=0;j<4;++j) {
            int c = col0 + tx*4 + j;
            float v = acc[i][j];
            if (ADDSRC) v += addCoef * as[(long)r*N + c];
            C[(long)r*N + c] = v;
        }
    }
}

static inline void gemm_nn_f32(hipStream_t st, const float*A,const float*B,float*C,
                               int M,int N,int K,long sA,long sB,long sC,int batch){
    dim3 g(N/64, M/64, batch);
    gemm_tile<0,false><<<g,256,0,st>>>(A,B,C,M,N,K,sA,sB,sC,nullptr,0,0.f);
}
static inline void gemm_nt_f32(hipStream_t st, const float*A,const float*B,float*C,
                               int M,int N,int K,long sA,long sB,long sC,int batch){
    dim3 g(N/64, M/64, batch);
    gemm_tile<1,false><<<g,256,0,st>>>(A,B,C,M,N,K,sA,sB,sC,nullptr,0,0.f);
}
static inline void gemm_nn_add_f32(hipStream_t st, const float*A,const float*B,float*C,
                                   int M,int N,int K,long sA,long sB,long sC,int batch,
                                   const float* addsrc, long sAdd, float coef){
    dim3 g(N/64, M/64, batch);
    gemm_tile<0,true><<<g,256,0,st>>>(A,B,C,M,N,K,sA,sB,sC,addsrc,sAdd,coef);
}

// ---------------- small fused kernels ----------------

__launch_bounds__(256)
__global__ void skinny_kernel(const float* __restrict__ x, const float* __restrict__ Wlr,
                              const float* __restrict__ Wm, const float* __restrict__ bm,
                              const float* __restrict__ Wsc, const float* __restrict__ bsc,
                              float* __restrict__ lr0, float* __restrict__ lr1, float* __restrict__ lr2,
                              float* __restrict__ momb, float* __restrict__ scb)
{
    int l = blockIdx.x;
    int tid = threadIdx.x, lane = tid & 63, w = tid >> 6;
    __shared__ float xr[DIM_];
    for (int i = tid; i < DIM_; i += 256) xr[i] = x[(size_t)l*DIM_ + i];
    __syncthreads();
    for (int o = w; o < 20; o += 4) {
        const float* W; int ld, col;
        if (o < 12)      { W = Wlr; ld = 12; col = o; }
        else if (o < 16) { W = Wm;  ld = 4;  col = o-12; }
        else             { W = Wsc; ld = 4;  col = o-16; }
        float p = 0.f;
        for (int i = lane; i < DIM_; i += 64) p += xr[i] * W[(size_t)i*ld + col];
        p = waveReduceSum(p);
        if (lane == 0) {
            if (o < 12) {
                int h = o/3, i3 = o%3;
                float v = softplusf_(p + BASE_LR_INV_F);
                (i3==0?lr0:(i3==1?lr1:lr2))[(size_t)h*L_SEQ + l] = v;
            } else if (o < 16) {
                int h = o-12; momb[(size_t)h*L_SEQ + l] = sigmoidf_(p + bm[h]);
            } else {
                int h = o-16; scb[(size_t)h*L_SEQ + l] = siluf_(p + bsc[h]);
            }
        }
    }
}

__launch_bounds__(256)
__global__ void mm_mean_kernel(const float* __restrict__ momb, float* __restrict__ mmb)
{
    int b = blockIdx.x; int ci = b / NH_; int h = b % NH_;
    float s = 0.f;
    for (int i = threadIdx.x; i < CHUNK_; i += 256)
        s += momb[(size_t)h*L_SEQ + ci*CHUNK_ + i];
    __shared__ float red[4];
    s = waveReduceSum(s);
    if ((threadIdx.x & 63) == 0) red[threadIdx.x >> 6] = s;
    __syncthreads();
    if (threadIdx.x == 0) mmb[b] = (red[0]+red[1]+red[2]+red[3]) / (float)CHUNK_;
}

__launch_bounds__(64)
__global__ void qkv_prep_kernel(const unsigned short* __restrict__ aqkv, float* __restrict__ qc,
                                float* __restrict__ kc, float* __restrict__ vc, int ci)
{
    int b = blockIdx.x; int h = b >> 10; int c = b & 1023;
    int l = ci*CHUNK_ + c;
    int lane = threadIdx.x;
    const unsigned short* base = aqkv + (size_t)l*QKV3 + (size_t)h*HD;
    int j0 = lane*8;
    float q[8], k[8], v[8]; float sq = 0.f, sk = 0.f;
    uint4 ua = *(const uint4*)(base + j0);
    uint4 ub = *(const uint4*)(base + 2048 + j0);
    uint4 uc = *(const uint4*)(base + 4096 + j0);
    unsigned int wa[4] = {ua.x,ua.y,ua.z,ua.w};
    unsigned int wb[4] = {ub.x,ub.y,ub.z,ub.w};
    unsigned int wc[4] = {uc.x,uc.y,uc.z,uc.w};
    #pragma unroll
    for (int t = 0; t < 4; ++t) {
        float a0 = bf2f(wa[t] & 0xffff), a1 = bf2f(wa[t] >> 16);
        float b0 = bf2f(wb[t] & 0xffff), b1 = bf2f(wb[t] >> 16);
        float c0 = bf2f(wc[t] & 0xffff), c1 = bf2f(wc[t] >> 16);
        float qs0 = siluf_(a0), qs1 = siluf_(a1);
        float ks0 = siluf_(b0), ks1 = siluf_(b1);
        q[2*t] = qs0; q[2*t+1] = qs1; sq += qs0*qs0 + qs1*qs1;
        k[2*t] = ks0; k[2*t+1] = ks1; sk += ks0*ks0 + ks1*ks1;
        v[2*t] = siluf_(c0); v[2*t+1] = siluf_(c1);
    }
    sq = waveReduceSum(sq); sk = waveReduceSum(sk);
    float rq = 1.f/(sqrtf(sq)+1e-5f), rk = 1.f/(sqrtf(sk)+1e-5f);
    size_t o = ((size_t)h*CHUNK_ + c)*HD + j0;
    #pragma unroll
    for (int t = 0; t < 8; t += 4) {
        float4 a = {q[t]*rq, q[t+1]*rq, q[t+2]*rq, q[t+3]*rq};
        float4 bb = {k[t]*rk, k[t+1]*rk, k[t+2]*rk, k[t+3]*rk};
        float4 cc = {v[t], v[t+1], v[t+2], v[t+3]};
        *(float4*)(qc + o + t) = a;
        *(float4*)(kc + o + t) = bb;
        *(float4*)(vc + o + t) = cc;
    }
}

__launch_bounds__(256)
__global__ void ew_gh_kernel(const float* __restrict__ A1, const float* __restrict__ B1,
                             float* __restrict__ D1, long n)
{
    for (long i = (long)blockIdx.x*blockDim.x + threadIdx.x; i < n; i += (long)gridDim.x*blockDim.x)
        D1[i] = siluf_(A1[i]) * B1[i];
}

__launch_bounds__(256)
__global__ void ew_bwd_kernel(float* __restrict__ A1, float* __restrict__ B1,
                              const float* __restrict__ C1, float* __restrict__ D1, long n)
{
    for (long i = (long)blockIdx.x*blockDim.x + threadIdx.x; i < n; i += (long)gridDim.x*blockDim.x) {
        float g = A1[i], hb = B1[i], dh = C1[i];
        float s = sigmoidf_(g);
        float sg = g*s;
        D1[i] = sg*hb;                       // hidden
        B1[i] = dh*sg;                       // dhbm
        float dy = dh*hb;
        A1[i] = dy*s*(1.f + g*(1.f-s));      // dgba
    }
}

__launch_bounds__(256)
__global__ void momentum_kernel(float* __restrict__ X, float* __restrict__ M,
                                const float* __restrict__ mm, long n)
{
    for (long i = (long)blockIdx.x*blockDim.x + threadIdx.x; i < n; i += (long)gridDim.x*blockDim.x) {
        int h = (int)((i >> 18) & 3);        // HD*HD = 2^18, NH=4
        float v = X[i] + M[i]*mm[h];
        X[i] = v; M[i] = v;
    }
}

__launch_bounds__(256)
__global__ void frob_kernel(const float* __restrict__ X, float* __restrict__ fro)
{
    int mtx = blockIdx.x;
    const float* base = X + (size_t)mtx*HD*HD;
    float ss = 0.f;
    for (int i = threadIdx.x; i < HD*HD; i += 256) { float v = base[i]; ss += v*v; }
    __shared__ float red[4];
    ss = waveReduceSum(ss);
    if ((threadIdx.x & 63) == 0) red[threadIdx.x >> 6] = ss;
    __syncthreads();
    if (threadIdx.x == 0) fro[mtx] = 1.f/(sqrtf(red[0]+red[1]+red[2]+red[3]) + 1e-7f);
}

__launch_bounds__(256)
__global__ void scalex_kernel(float* __restrict__ X, const float* __restrict__ fro, long n)
{
    for (long i = (long)blockIdx.x*blockDim.x + threadIdx.x; i < n; i += (long)gridDim.x*blockDim.x)
        X[i] *= fro[i >> 18];
}

__launch_bounds__(256)
__global__ void ns_ew_kernel(float* __restrict__ AB, const float* __restrict__ TB,
                             float bcoef, float ccoef, long n)
{
    for (long i = (long)blockIdx.x*blockDim.x + threadIdx.x; i < n; i += (long)gridDim.x*blockDim.x)
        AB[i] = bcoef*AB[i] + ccoef*TB[i];
}

__launch_bounds__(64)
__global__ void norm_rows_kernel(const float* __restrict__ W, float* __restrict__ NV)
{
    int r = blockIdx.x;
    int lane = threadIdx.x;
    const float* row = W + (size_t)r*HD;
    float ss = 0.f;
    int j0 = lane*8;
    #pragma unroll
    for (int t = 0; t < 8; ++t) { float v = row[j0+t]; ss += v*v; }
    ss = waveReduceSum(ss);
    if (lane == 0) NV[r] = sqrtf(ss);
}

__launch_bounds__(64)
__global__ void renorm_kernel(float* __restrict__ W, const float* __restrict__ X,
                              const float* __restrict__ NV)
{
    int r = blockIdx.x;
    int lane = threadIdx.x;
    float* wrow = W + (size_t)r*HD;
    const float* xrow = X + (size_t)r*HD;
    int j0 = lane*8;
    float v[8]; float ss = 0.f;
    #pragma unroll
    for (int t = 0; t < 8; ++t) { v[t] = wrow[j0+t] + xrow[j0+t]; ss += v[t]*v[t]; }
    ss = waveReduceSum(ss);
    float s = NV[r] / (sqrtf(ss) + 1e-5f);
    #pragma unroll
    for (int t = 0; t < 8; ++t) wrow[j0+t] = v[t]*s;
}

__launch_bounds__(64)
__global__ void ttt_post_kernel(float* __restrict__ pre, const float* __restrict__ scb,
                                const float* __restrict__ g)
{
    int b = blockIdx.x; int h = b >> 12; int l = b & 4095;
    int lane = threadIdx.x;
    float* row = pre + (size_t)l*DIM_ + (size_t)h*HD;
    int j0 = lane*8;
    float v[8]; float ss = 0.f;
    #pragma unroll
    for (int t = 0; t < 8; ++t) { v[t] = row[j0+t]; ss += v[t]*v[t]; }
    ss = waveReduceSum(ss);
    float inv = rsqrtf(ss/(float)HD + 1e-5f) * scb[(size_t)h*L_SEQ + l];
    #pragma unroll
    for (int t = 0; t < 8; ++t) row[j0+t] = v[t]*inv*g[j0+t];
}

// sliding-window causal attention over bf16 qkv, one block per (query, head)
__launch_bounds__(256)
__global__ void attn_kernel(const unsigned short* __restrict__ aqkv, const float* __restrict__ qk_scale,
                            const float* __restrict__ qk_offset, float* __restrict__ pre)
{
    int qpos = blockIdx.x;
    int head = blockIdx.y;
    int tid = threadIdx.x, lane = tid & 63, w = tid >> 6;
    int ch = head*AHD + lane*2;
    float4 scv = *(const float4*)(qk_scale + (size_t)ch*2);
    float4 ofv = *(const float4*)(qk_offset + (size_t)ch*2);
    const unsigned short* qrow = aqkv + (size_t)qpos*QKV3;
    unsigned int qw = *(const unsigned int*)(qrow + ch);
    float q0 = bf2f(qw & 0xffff)*scv.x + ofv.x;
    float q1 = bf2f(qw >> 16)*scv.z + ofv.z;
    int kstart = qpos - WIN; if (kstart < 0) kstart = 0;
    float m = -INFINITY, lsum = 0.f, a0 = 0.f, a1 = 0.f;
    for (int kp = kstart + w; kp <= qpos; kp += 4) {
        const unsigned short* krow = aqkv + (size_t)kp*QKV3;
        unsigned int kw = *(const unsigned int*)(krow + DIM_ + ch);
        float kv0 = bf2f(kw & 0xffff)*scv.y + ofv.y;
        float kv1 = bf2f(kw >> 16)*scv.w + ofv.w;
        float d = q0*kv0 + q1*kv1;
        d = waveReduceSum(d);
        float s = d * 0.088388347648318447f;   // 1/sqrt(128)
        float mnew = fmaxf(m, s);
        float corr = expf(m - mnew);
        float p = expf(s - mnew);
        unsigned int vw = *(const unsigned int*)(krow + 2*DIM_ + ch);
        lsum = lsum*corr + p;
        a0 = a0*corr + p*bf2f(vw & 0xffff);
        a1 = a1*corr + p*bf2f(vw >> 16);
        m = mnew;
    }
    __shared__ float sm[4], sl[4], sa[4][AHD];
    sa[w][lane*2] = a0; sa[w][lane*2+1] = a1;
    if (lane == 0) { sm[w] = m; sl[w] = lsum; }
    __syncthreads();
    if (tid < AHD) {
        float M = fmaxf(fmaxf(sm[0],sm[1]), fmaxf(sm[2],sm[3]));
        float Ls = 0.f, o = 0.f;
        #pragma unroll
        for (int i = 0; i < 4; ++i) {
            float e = expf(sm[i] - M);
            Ls += sl[i]*e;
            o  += sa[i][tid]*e;
        }
        pre[(size_t)qpos*DIM_ + (size_t)head*AHD + tid] += o / Ls;
    }
}

// ---------------- host ----------------
extern "C" void kernel_launch(void* const* d_in, const int* in_sizes, int n_in,
                              void* d_out, int out_size, void* d_ws, size_t ws_size,
                              hipStream_t stream)
{
    (void)in_sizes; (void)n_in; (void)out_size; (void)ws_size;
    const float* x        = (const float*)d_in[0];
    const float* Wqkv     = (const float*)d_in[1];
    const float* Wlr      = (const float*)d_in[2];
    const float* Wm       = (const float*)d_in[3];
    const float* bm       = (const float*)d_in[4];
    const float* Wsc      = (const float*)d_in[5];
    const float* bsc      = (const float*)d_in[6];
    const float* Wo       = (const float*)d_in[7];
    const float* w0       = (const float*)d_in[8];
    const float* w1       = (const float*)d_in[9];
    const float* w2       = (const float*)d_in[10];
    const float* o_norm_g = (const float*)d_in[11];
    const float* qk_scale = (const float*)d_in[12];
    const float* qk_offset= (const float*)d_in[13];
    float* out = (float*)d_out;

    const long HDHD = (long)HD*HD;              // 262144
    const long CH_HD = (long)CHUNK_*HD;         // 524288

    char* pc = (char*)d_ws;
    unsigned short* AQKV = (unsigned short*)pc; pc += (size_t)L_SEQ*QKV3*sizeof(unsigned short);
    float* PRE  = (float*)pc; pc += (size_t)L_SEQ*DIM_*sizeof(float);
    float* KC   = (float*)pc; pc += (size_t)NH_*CH_HD*sizeof(float);
    float* VC   = (float*)pc; pc += (size_t)NH_*CH_HD*sizeof(float);
    float* A1   = (float*)pc; pc += (size_t)NH_*CH_HD*sizeof(float);
    float* B1   = (float*)pc; pc += (size_t)NH_*CH_HD*sizeof(float);
    float* D1   = (float*)pc; pc += (size_t)NH_*CH_HD*sizeof(float);
    float* QCC1 = (float*)pc; pc += (size_t)NH_*CH_HD*sizeof(float);   // QC, then dhidden
    float* WST  = (float*)pc; pc += (size_t)3*NH_*HDHD*sizeof(float);
    float* MST  = (float*)pc; pc += (size_t)3*NH_*HDHD*sizeof(float);
    float* XB   = (float*)pc; pc += (size_t)3*NH_*HDHD*sizeof(float);
    float* AB   = (float*)pc; pc += (size_t)3*NH_*HDHD*sizeof(float);
    float* TB   = (float*)pc; pc += (size_t)3*NH_*HDHD*sizeof(float);
    float* NV   = (float*)pc; pc += (size_t)3*NH_*HD*sizeof(float);
    float* LR0  = (float*)pc; pc += (size_t)NH_*L_SEQ*sizeof(float);
    float* LR1  = (float*)pc; pc += (size_t)NH_*L_SEQ*sizeof(float);
    float* LR2  = (float*)pc; pc += (size_t)NH_*L_SEQ*sizeof(float);
    float* MOMB = (float*)pc; pc += (size_t)NH_*L_SEQ*sizeof(float);
    float* SCB  = (float*)pc; pc += (size_t)NH_*L_SEQ*sizeof(float);
    float* MMB  = (float*)pc; pc += (size_t)NC_*NH_*sizeof(float);
    float* FRO  = (float*)pc; pc += 16*sizeof(float);
    // total ~197.6 MB

    // 1. attn_qkv = x @ Wqkv (MFMA, bf16 store)
    launch_mfma<0,0,false,true>(stream, x, Wqkv, AQKV, L_SEQ, QKV3, DIM_, QKV3, 0,0,0, 1);

    // 2. lr / mom / scale skinny projections
    skinny_kernel<<<L_SEQ,256,0,stream>>>(x, Wlr, Wm, bm, Wsc, bsc, LR0,LR1,LR2, MOMB, SCB);
    mm_mean_kernel<<<NC_*NH_,256,0,stream>>>(MOMB, MMB);

    // 3. init TTT states
    size_t wbytes = (size_t)NH_*HDHD*sizeof(float);
    hipMemcpyAsync(WST,              w0, wbytes, hipMemcpyDeviceToDevice, stream);
    hipMemcpyAsync(WST + NH_*HDHD,   w1, wbytes, hipMemcpyDeviceToDevice, stream);
    hipMemcpyAsync(WST + 2*NH_*HDHD, w2, wbytes, hipMemcpyDeviceToDevice, stream);
    hipMemsetAsync(MST, 0, 3*wbytes, stream);
    norm_rows_kernel<<<3*NH_*HD,64,0,stream>>>(WST, NV);

    const float nsA[5] = {4.0848f, 3.9505f, 3.7418f, 2.8769f, 2.8366f};
    const float nsB[5] = {-6.8946f,-6.3029f,-5.5913f,-3.1427f,-3.0525f};
    const float nsC[5] = {2.927f,  2.6377f, 2.3037f, 1.2046f, 1.2012f};

    // 4. sequential chunk scan
    for (int ci = 0; ci < NC_; ++ci) {
        qkv_prep_kernel<<<NH_*CHUNK_,64,0,stream>>>(AQKV, QCC1, KC, VC, ci);
        float* W0s = WST;
        float* W1s = WST + NH_*HDHD;
        float* W2s = WST + 2*NH_*HDHD;
        // forward (MFMA NT)
        launch_mfma<0,1,false,false>(stream, QCC1, W0s, A1, CHUNK_, HD, HD, HD, CH_HD, HDHD, CH_HD, NH_); // gba_q
        launch_mfma<0,1,false,false>(stream, QCC1, W2s, B1, CHUNK_, HD, HD, HD, CH_HD, HDHD, CH_HD, NH_); // hid
        ew_gh_kernel<<<4096,256,0,stream>>>(A1, B1, D1, (long)NH_*CH_HD);                                 // gh
        launch_mfma<0,1,false,false>(stream, D1, W1s, PRE + (size_t)ci*CHUNK_*DIM_,
                                     CHUNK_, HD, HD, DIM_, CH_HD, HDHD, HD, NH_);                         // out -> PRE cols
        // backward
        launch_mfma<0,1,false,false>(stream, KC, W0s, A1, CHUNK_, HD, HD, HD, CH_HD, HDHD, CH_HD, NH_);   // gba
        launch_mfma<0,1,false,false>(stream, KC, W2s, B1, CHUNK_, HD, HD, HD, CH_HD, HDHD, CH_HD, NH_);   // hbm
        launch_mfma<0,0,false,false>(stream, VC, W1s, QCC1, CHUNK_, HD, HD, HD, CH_HD, HDHD, CH_HD, NH_); // dhidden
        ew_bwd_kernel<<<4096,256,0,stream>>>(A1, B1, QCC1, D1, (long)NH_*CH_HD);  // ->dgba,dhbm,hidden
        // dw matrices (MFMA TN + k-scale)
        launch_mfma<1,0,true,false>(stream, A1, KC, XB,              HD, HD, CHUNK_, HD, CH_HD, CH_HD, HDHD, NH_, LR0 + ci*CHUNK_, (long)L_SEQ);
        launch_mfma<1,0,true,false>(stream, VC, D1, XB + NH_*HDHD,   HD, HD, CHUNK_, HD, CH_HD, CH_HD, HDHD, NH_, LR1 + ci*CHUNK_, (long)L_SEQ);
        launch_mfma<1,0,true,false>(stream, B1, KC, XB + 2*NH_*HDHD, HD, HD, CHUNK_, HD, CH_HD, CH_HD, HDHD, NH_, LR2 + ci*CHUNK_, (long)L_SEQ);
        // momentum add + store new momentum
        momentum_kernel<<<4096,256,0,stream>>>(XB, MST, MMB + ci*NH_, 3L*NH_*HDHD);
        // Newton-Schulz (fp32, batched over 12 matrices)
        frob_kernel<<<12,256,0,stream>>>(XB, FRO);
        scalex_kernel<<<4096,256,0,stream>>>(XB, FRO, 3L*NH_*HDHD);
        float* Xc = XB; float* Tc = TB;
        for (int it = 0; it < 5; ++it) {
            gemm_nt_f32(stream, Xc, Xc, AB, HD,HD,HD, HDHD,HDHD,HDHD, 12);                    // A = X X^T
            gemm_nn_f32(stream, AB, AB, Tc, HD,HD,HD, HDHD,HDHD,HDHD, 12);                    // T = A A
            ns_ew_kernel<<<4096,256,0,stream>>>(AB, Tc, nsB[it], nsC[it], 3L*NH_*HDHD);       // A' = b*A + c*T
            gemm_nn_add_f32(stream, AB, Xc, Tc, HD,HD,HD, HDHD,HDHD,HDHD, 12, Xc, HDHD, nsA[it]); // X' = A'X + a*X
            float* t_ = Xc; Xc = Tc; Tc = t_;
        }
        // W = renorm(W + NS(dw), n)
        renorm_kernel<<<3*NH_*HD,64,0,stream>>>(WST, Xc, NV);
    }

    // 5. TTT post: in-place rms-norm * g * scale on PRE
    ttt_post_kernel<<<NH_*L_SEQ,64,0,stream>>>(PRE, SCB, o_norm_g);

    // 6. sliding-window attention adds into PRE
    attn_kernel<<<dim3(L_SEQ, NAH_),256,0,stream>>>(AQKV, qk_scale, qk_offset, PRE);

    // 7. final projection (MFMA, fp32 out)
    launch_mfma<0,0,false,false>(stream, PRE, Wo, out, L_SEQ, DIM_, DIM_, DIM_, 0,0,0, 1);
}

// Round 9
// 6415.459 us; speedup vs baseline: 1.7143x; 1.7143x over previous
//
#include <hip/hip_runtime.h>
#include <cmath>

#define L_SEQ 4096
#define DIM_  2048
#define QKV3  6144
#define HD    512
#define NH_   4
#define CHUNK_ 1024
#define NC_   4
#define NAH_  16
#define AHD   128
#define WIN   1024

static constexpr float BASE_LR_INV_F = -4.6001660298893f; // 0.01 + log(-expm1(-0.01))

__device__ __forceinline__ float sigmoidf_(float x){ return 1.0f/(1.0f+expf(-x)); }
__device__ __forceinline__ float siluf_(float x){ return x/(1.0f+expf(-x)); }
__device__ __forceinline__ float softplusf_(float x){ return (x>20.f)? x : log1pf(expf(x)); }

__device__ __forceinline__ float bf2f(unsigned short b){
    union { unsigned int u; float f; } x; x.u = ((unsigned int)b) << 16; return x.f;
}
__device__ __forceinline__ unsigned short f2bf(float f){
    union { float f; unsigned int u; } x; x.f = f;
    unsigned int r = x.u + 0x7fff + ((x.u >> 16) & 1);   // RNE
    return (unsigned short)(r >> 16);
}

__device__ __forceinline__ float waveReduceSum(float v){
    #pragma unroll
    for (int s=32; s; s>>=1) v += __shfl_xor(v, s, 64);
    return v;
}

typedef __attribute__((ext_vector_type(8))) short  bfrag;   // 8 bf16 = 4 VGPR
typedef __attribute__((ext_vector_type(4))) float  f32x4;   // 4 fp32

// ================= bf16 MFMA GEMM (fp32 in, fp32/bf16 out) =================
template<bool C16_>
__device__ __forceinline__ void store_frag(void* Cv, long base, int ldc, int gr0, int gc, f32x4 v){
    #pragma unroll
    for (int r = 0; r < 4; ++r) {
        float f = v[r];
        if (C16_) ((unsigned short*)Cv)[base + (long)(gr0+r)*ldc + gc] = f2bf(f);
        else      ((float*)Cv)[base + (long)(gr0+r)*ldc + gc] = f;
    }
}

template<int OPA, int OPB, bool KSCALE, bool C16>
__launch_bounds__(256)
__global__ void gemm_mfma(const float* __restrict__ A, const float* __restrict__ B,
                          void* __restrict__ Cv, int M, int N, int K, int ldc,
                          long sA, long sB, long sC,
                          const float* __restrict__ kscale, long sKs)
{
    const int bz = blockIdx.z;
    A += (long)bz * sA;  B += (long)bz * sB;
    const float* sc = KSCALE ? (kscale + (long)bz * sKs) : nullptr;

    const int row0 = blockIdx.y * 64;
    const int col0 = blockIdx.x * 64;
    const int tid = threadIdx.x, lane = tid & 63, w = tid >> 6;
    const int wr = (w >> 1) * 32, wc = (w & 1) * 32;
    const int lda = OPA ? M : K;
    const int ldb = OPB ? K : N;

    __shared__ __align__(16) short As[64][40];
    __shared__ __align__(16) short Bs[64][40];

    f32x4 acc00{0.f,0.f,0.f,0.f}, acc01{0.f,0.f,0.f,0.f};
    f32x4 acc10{0.f,0.f,0.f,0.f}, acc11{0.f,0.f,0.f,0.f};

    for (int k0 = 0; k0 < K; k0 += 32) {
        if (OPA == 0) {
            int r = tid >> 2, kk = (tid & 3) * 8;
            const float* src = A + (long)(row0 + r)*lda + k0 + kk;
            float4 v0 = *(const float4*)src, v1 = *(const float4*)(src + 4);
            unsigned int p0 = (unsigned)f2bf(v0.x) | ((unsigned)f2bf(v0.y) << 16);
            unsigned int p1 = (unsigned)f2bf(v0.z) | ((unsigned)f2bf(v0.w) << 16);
            unsigned int p2 = (unsigned)f2bf(v1.x) | ((unsigned)f2bf(v1.y) << 16);
            unsigned int p3 = (unsigned)f2bf(v1.z) | ((unsigned)f2bf(v1.w) << 16);
            *(uint4*)&As[r][kk] = make_uint4(p0, p1, p2, p3);
        } else {
            int kk = tid >> 3, r0 = (tid & 7) * 8;
            const float* src = A + (long)(k0 + kk)*lda + row0 + r0;
            float4 v0 = *(const float4*)src, v1 = *(const float4*)(src + 4);
            float vv[8] = {v0.x,v0.y,v0.z,v0.w,v1.x,v1.y,v1.z,v1.w};
            #pragma unroll
            for (int j = 0; j < 8; ++j) As[r0+j][kk] = (short)f2bf(vv[j]);
        }
        if (OPB == 1) {
            int c = tid >> 2, kk = (tid & 3) * 8;
            const float* src = B + (long)(col0 + c)*ldb + k0 + kk;
            float4 v0 = *(const float4*)src, v1 = *(const float4*)(src + 4);
            unsigned int p0 = (unsigned)f2bf(v0.x) | ((unsigned)f2bf(v0.y) << 16);
            unsigned int p1 = (unsigned)f2bf(v0.z) | ((unsigned)f2bf(v0.w) << 16);
            unsigned int p2 = (unsigned)f2bf(v1.x) | ((unsigned)f2bf(v1.y) << 16);
            unsigned int p3 = (unsigned)f2bf(v1.z) | ((unsigned)f2bf(v1.w) << 16);
            *(uint4*)&Bs[c][kk] = make_uint4(p0, p1, p2, p3);
        } else {
            int kk = tid >> 3, c0 = (tid & 7) * 8;
            const float* src = B + (long)(k0 + kk)*ldb + col0 + c0;
            float4 v0 = *(const float4*)src, v1 = *(const float4*)(src + 4);
            float vv[8] = {v0.x,v0.y,v0.z,v0.w,v1.x,v1.y,v1.z,v1.w};
            if (KSCALE) {
                float s = sc[k0 + kk];
                #pragma unroll
                for (int j = 0; j < 8; ++j) vv[j] *= s;
            }
            #pragma unroll
            for (int j = 0; j < 8; ++j) Bs[c0+j][kk] = (short)f2bf(vv[j]);
        }
        __syncthreads();
        {
            const int fr = lane & 15, fk = (lane >> 4) * 8;
            bfrag a0 = *(const bfrag*)&As[wr      + fr][fk];
            bfrag a1 = *(const bfrag*)&As[wr + 16 + fr][fk];
            bfrag b0 = *(const bfrag*)&Bs[wc      + fr][fk];
            bfrag b1 = *(const bfrag*)&Bs[wc + 16 + fr][fk];
            acc00 = __builtin_amdgcn_mfma_f32_16x16x32_bf16(a0, b0, acc00, 0, 0, 0);
            acc01 = __builtin_amdgcn_mfma_f32_16x16x32_bf16(a0, b1, acc01, 0, 0, 0);
            acc10 = __builtin_amdgcn_mfma_f32_16x16x32_bf16(a1, b0, acc10, 0, 0, 0);
            acc11 = __builtin_amdgcn_mfma_f32_16x16x32_bf16(a1, b1, acc11, 0, 0, 0);
        }
        __syncthreads();
    }
    const int oc = lane & 15, orr = (lane >> 4) * 4;
    const long base = (long)bz * sC;
    store_frag<C16>(Cv, base, ldc, row0 + wr      + orr, col0 + wc      + oc, acc00);
    store_frag<C16>(Cv, base, ldc, row0 + wr      + orr, col0 + wc + 16 + oc, acc01);
    store_frag<C16>(Cv, base, ldc, row0 + wr + 16 + orr, col0 + wc      + oc, acc10);
    store_frag<C16>(Cv, base, ldc, row0 + wr + 16 + orr, col0 + wc + 16 + oc, acc11);
}

template<int OPA, int OPB, bool KSCALE, bool C16>
static inline void launch_mfma(hipStream_t st, const float* A, const float* B, void* C,
                               int M, int N, int K, int ldc, long sA, long sB, long sC, int batch,
                               const float* ks = nullptr, long sKs = 0){
    dim3 g(N/64, M/64, batch);
    gemm_mfma<OPA,OPB,KSCALE,C16><<<g,256,0,st>>>(A,B,C,M,N,K,ldc,sA,sB,sC,ks,sKs);
}

// ================= fp32 tiled GEMM (Newton-Schulz only) =================
template<int OPB, bool ADDSRC>
__launch_bounds__(256)
__global__ void gemm_tile(const float* __restrict__ A, const float* __restrict__ B,
                          float* __restrict__ C, int M, int N, int K,
                          long sA, long sB, long sC,
                          const float* __restrict__ addsrc, long sAdd, float addCoef)
{
    const int bz = blockIdx.z;
    A += (long)bz * sA;  B += (long)bz * sB;  C += (long)bz * sC;
    const float* as = ADDSRC ? (addsrc + (long)bz * sAdd) : nullptr;

    const int row0 = blockIdx.y * 64;
    const int col0 = blockIdx.x * 64;
    const int tid = threadIdx.x;
    const int tx = tid & 15, ty = tid >> 4;

    __shared__ float As[16][68];
    __shared__ float Bs[16][68];

    float acc[4][4] = {};
    const int lda = K;
    const int ldb = OPB ? K : N;

    for (int k0 = 0; k0 < K; k0 += 16) {
        {
            int linear = tid * 4;
            int r = linear >> 4, kk = linear & 15;
            float4 v = *(const float4*)(A + (long)(row0 + r)*lda + k0 + kk);
            As[kk+0][r]=v.x; As[kk+1][r]=v.y; As[kk+2][r]=v.z; As[kk+3][r]=v.w;
        }
        {
            int linear = tid * 4;
            if (OPB == 0) {
                int kk = linear >> 6, c = linear & 63;
                float4 v = *(const float4*)(B + (long)(k0 + kk)*ldb + col0 + c);
                Bs[kk][c+0]=v.x; Bs[kk][c+1]=v.y; Bs[kk][c+2]=v.z; Bs[kk][c+3]=v.w;
            } else {
                int c = linear >> 4, kk = linear & 15;
                float4 v = *(const float4*)(B + (long)(col0 + c)*ldb + k0 + kk);
                Bs[kk+0][c]=v.x; Bs[kk+1][c]=v.y; Bs[kk+2][c]=v.z; Bs[kk+3][c]=v.w;
            }
        }
        __syncthreads();
        #pragma unroll
        for (int kk = 0; kk < 16; ++kk) {
            float a[4], b[4];
            #pragma unroll
            for (int i=0;i<4;++i) a[i] = As[kk][ty*4+i];
            #pragma unroll
            for (int j=0;j<4;++j) b[j] = Bs[kk][tx*4+j];
            #pragma unroll
            for (int i=0;i<4;++i)
                #pragma unroll
                for (int j=0;j<4;++j) acc[i][j] += a[i]*b[j];
        }
        __syncthreads();
    }
    #pragma unroll
    for (int i=0;i<4;++i) {
        int r = row0 + ty*4 + i;
        #pragma unroll
        for (int j=0;j<4;++j) {
            int c = col0 + tx*4 + j;
            float v = acc[i][j];
            if (ADDSRC) v += addCoef * as[(long)r*N + c];
            C[(long)r*N + c] = v;
        }
    }
}

static inline void gemm_nn_f32(hipStream_t st, const float*A,const float*B,float*C,
                               int M,int N,int K,long sA,long sB,long sC,int batch){
    dim3 g(N/64, M/64, batch);
    gemm_tile<0,false><<<g,256,0,st>>>(A,B,C,M,N,K,sA,sB,sC,nullptr,0,0.f);
}
static inline void gemm_nt_f32(hipStream_t st, const float*A,const float*B,float*C,
                               int M,int N,int K,long sA,long sB,long sC,int batch){
    dim3 g(N/64, M/64, batch);
    gemm_tile<1,false><<<g,256,0,st>>>(A,B,C,M,N,K,sA,sB,sC,nullptr,0,0.f);
}
static inline void gemm_nn_add_f32(hipStream_t st, const float*A,const float*B,float*C,
                                   int M,int N,int K,long sA,long sB,long sC,int batch,
                                   const float* addsrc, long sAdd, float coef){
    dim3 g(N/64, M/64, batch);
    gemm_tile<0,true><<<g,256,0,st>>>(A,B,C,M,N,K,sA,sB,sC,addsrc,sAdd,coef);
}

// ---------------- small fused kernels ----------------

__launch_bounds__(256)
__global__ void skinny_kernel(const float* __restrict__ x, const float* __restrict__ Wlr,
                              const float* __restrict__ Wm, const float* __restrict__ bm,
                              const float* __restrict__ Wsc, const float* __restrict__ bsc,
                              float* __restrict__ lr0, float* __restrict__ lr1, float* __restrict__ lr2,
                              float* __restrict__ momb, float* __restrict__ scb)
{
    int l = blockIdx.x;
    int tid = threadIdx.x, lane = tid & 63, w = tid >> 6;
    __shared__ float xr[DIM_];
    for (int i = tid; i < DIM_; i += 256) xr[i] = x[(size_t)l*DIM_ + i];
    __syncthreads();
    for (int o = w; o < 20; o += 4) {
        const float* W; int ld, col;
        if (o < 12)      { W = Wlr; ld = 12; col = o; }
        else if (o < 16) { W = Wm;  ld = 4;  col = o-12; }
        else             { W = Wsc; ld = 4;  col = o-16; }
        float p = 0.f;
        for (int i = lane; i < DIM_; i += 64) p += xr[i] * W[(size_t)i*ld + col];
        p = waveReduceSum(p);
        if (lane == 0) {
            if (o < 12) {
                int h = o/3, i3 = o%3;
                float v = softplusf_(p + BASE_LR_INV_F);
                (i3==0?lr0:(i3==1?lr1:lr2))[(size_t)h*L_SEQ + l] = v;
            } else if (o < 16) {
                int h = o-12; momb[(size_t)h*L_SEQ + l] = sigmoidf_(p + bm[h]);
            } else {
                int h = o-16; scb[(size_t)h*L_SEQ + l] = siluf_(p + bsc[h]);
            }
        }
    }
}

__launch_bounds__(256)
__global__ void mm_mean_kernel(const float* __restrict__ momb, float* __restrict__ mmb)
{
    int b = blockIdx.x; int ci = b / NH_; int h = b % NH_;
    float s = 0.f;
    for (int i = threadIdx.x; i < CHUNK_; i += 256)
        s += momb[(size_t)h*L_SEQ + ci*CHUNK_ + i];
    __shared__ float red[4];
    s = waveReduceSum(s);
    if ((threadIdx.x & 63) == 0) red[threadIdx.x >> 6] = s;
    __syncthreads();
    if (threadIdx.x == 0) mmb[b] = (red[0]+red[1]+red[2]+red[3]) / (float)CHUNK_;
}

__launch_bounds__(64)
__global__ void qkv_prep_kernel(const unsigned short* __restrict__ aqkv, float* __restrict__ qc,
                                float* __restrict__ kc, float* __restrict__ vc, int ci)
{
    int b = blockIdx.x; int h = b >> 10; int c = b & 1023;
    int l = ci*CHUNK_ + c;
    int lane = threadIdx.x;
    const unsigned short* base = aqkv + (size_t)l*QKV3 + (size_t)h*HD;
    int j0 = lane*8;
    float q[8], k[8], v[8]; float sq = 0.f, sk = 0.f;
    uint4 ua = *(const uint4*)(base + j0);
    uint4 ub = *(const uint4*)(base + 2048 + j0);
    uint4 uc = *(const uint4*)(base + 4096 + j0);
    unsigned int wa[4] = {ua.x,ua.y,ua.z,ua.w};
    unsigned int wb[4] = {ub.x,ub.y,ub.z,ub.w};
    unsigned int wc[4] = {uc.x,uc.y,uc.z,uc.w};
    #pragma unroll
    for (int t = 0; t < 4; ++t) {
        float a0 = bf2f(wa[t] & 0xffff), a1 = bf2f(wa[t] >> 16);
        float b0 = bf2f(wb[t] & 0xffff), b1 = bf2f(wb[t] >> 16);
        float c0 = bf2f(wc[t] & 0xffff), c1 = bf2f(wc[t] >> 16);
        float qs0 = siluf_(a0), qs1 = siluf_(a1);
        float ks0 = siluf_(b0), ks1 = siluf_(b1);
        q[2*t] = qs0; q[2*t+1] = qs1; sq += qs0*qs0 + qs1*qs1;
        k[2*t] = ks0; k[2*t+1] = ks1; sk += ks0*ks0 + ks1*ks1;
        v[2*t] = siluf_(c0); v[2*t+1] = siluf_(c1);
    }
    sq = waveReduceSum(sq); sk = waveReduceSum(sk);
    float rq = 1.f/(sqrtf(sq)+1e-5f), rk = 1.f/(sqrtf(sk)+1e-5f);
    size_t o = ((size_t)h*CHUNK_ + c)*HD + j0;
    #pragma unroll
    for (int t = 0; t < 8; t += 4) {
        float4 a = {q[t]*rq, q[t+1]*rq, q[t+2]*rq, q[t+3]*rq};
        float4 bb = {k[t]*rk, k[t+1]*rk, k[t+2]*rk, k[t+3]*rk};
        float4 cc = {v[t], v[t+1], v[t+2], v[t+3]};
        *(float4*)(qc + o + t) = a;
        *(float4*)(kc + o + t) = bb;
        *(float4*)(vc + o + t) = cc;
    }
}

__launch_bounds__(256)
__global__ void ew_gh_kernel(const float* __restrict__ A1, const float* __restrict__ B1,
                             float* __restrict__ D1, long n)
{
    for (long i = (long)blockIdx.x*blockDim.x + threadIdx.x; i < n; i += (long)gridDim.x*blockDim.x)
        D1[i] = siluf_(A1[i]) * B1[i];
}

__launch_bounds__(256)
__global__ void ew_bwd_kernel(float* __restrict__ A1, float* __restrict__ B1,
                              const float* __restrict__ C1, float* __restrict__ D1, long n)
{
    for (long i = (long)blockIdx.x*blockDim.x + threadIdx.x; i < n; i += (long)gridDim.x*blockDim.x) {
        float g = A1[i], hb = B1[i], dh = C1[i];
        float s = sigmoidf_(g);
        float sg = g*s;
        D1[i] = sg*hb;
        B1[i] = dh*sg;
        float dy = dh*hb;
        A1[i] = dy*s*(1.f + g*(1.f-s));
    }
}

__launch_bounds__(256)
__global__ void momentum_kernel(float* __restrict__ X, float* __restrict__ M,
                                const float* __restrict__ mm, long n)
{
    for (long i = (long)blockIdx.x*blockDim.x + threadIdx.x; i < n; i += (long)gridDim.x*blockDim.x) {
        int h = (int)((i >> 18) & 3);
        float v = X[i] + M[i]*mm[h];
        X[i] = v; M[i] = v;
    }
}

__launch_bounds__(256)
__global__ void frob_kernel(const float* __restrict__ X, float* __restrict__ fro)
{
    int mtx = blockIdx.x;
    const float* base = X + (size_t)mtx*HD*HD;
    float ss = 0.f;
    for (int i = threadIdx.x; i < HD*HD; i += 256) { float v = base[i]; ss += v*v; }
    __shared__ float red[4];
    ss = waveReduceSum(ss);
    if ((threadIdx.x & 63) == 0) red[threadIdx.x >> 6] = ss;
    __syncthreads();
    if (threadIdx.x == 0) fro[mtx] = 1.f/(sqrtf(red[0]+red[1]+red[2]+red[3]) + 1e-7f);
}

__launch_bounds__(256)
__global__ void scalex_kernel(float* __restrict__ X, const float* __restrict__ fro, long n)
{
    for (long i = (long)blockIdx.x*blockDim.x + threadIdx.x; i < n; i += (long)gridDim.x*blockDim.x)
        X[i] *= fro[i >> 18];
}

__launch_bounds__(256)
__global__ void ns_ew_kernel(float* __restrict__ AB, const float* __restrict__ TB,
                             float bcoef, float ccoef, long n)
{
    for (long i = (long)blockIdx.x*blockDim.x + threadIdx.x; i < n; i += (long)gridDim.x*blockDim.x)
        AB[i] = bcoef*AB[i] + ccoef*TB[i];
}

__launch_bounds__(64)
__global__ void norm_rows_kernel(const float* __restrict__ W, float* __restrict__ NV)
{
    int r = blockIdx.x;
    int lane = threadIdx.x;
    const float* row = W + (size_t)r*HD;
    float ss = 0.f;
    int j0 = lane*8;
    #pragma unroll
    for (int t = 0; t < 8; ++t) { float v = row[j0+t]; ss += v*v; }
    ss = waveReduceSum(ss);
    if (lane == 0) NV[r] = sqrtf(ss);
}

__launch_bounds__(64)
__global__ void renorm_kernel(float* __restrict__ W, const float* __restrict__ X,
                              const float* __restrict__ NV)
{
    int r = blockIdx.x;
    int lane = threadIdx.x;
    float* wrow = W + (size_t)r*HD;
    const float* xrow = X + (size_t)r*HD;
    int j0 = lane*8;
    float v[8]; float ss = 0.f;
    #pragma unroll
    for (int t = 0; t < 8; ++t) { v[t] = wrow[j0+t] + xrow[j0+t]; ss += v[t]*v[t]; }
    ss = waveReduceSum(ss);
    float s = NV[r] / (sqrtf(ss) + 1e-5f);
    #pragma unroll
    for (int t = 0; t < 8; ++t) wrow[j0+t] = v[t]*s;
}

__launch_bounds__(64)
__global__ void ttt_post_kernel(float* __restrict__ pre, const float* __restrict__ scb,
                                const float* __restrict__ g)
{
    int b = blockIdx.x; int h = b >> 12; int l = b & 4095;
    int lane = threadIdx.x;
    float* row = pre + (size_t)l*DIM_ + (size_t)h*HD;
    int j0 = lane*8;
    float v[8]; float ss = 0.f;
    #pragma unroll
    for (int t = 0; t < 8; ++t) { v[t] = row[j0+t]; ss += v[t]*v[t]; }
    ss = waveReduceSum(ss);
    float inv = rsqrtf(ss/(float)HD + 1e-5f) * scb[(size_t)h*L_SEQ + l];
    #pragma unroll
    for (int t = 0; t < 8; ++t) row[j0+t] = v[t]*inv*g[j0+t];
}

// ========== MFMA flash sliding-window attention ==========
// grid (L/64, NAH); 256 thr = 4 waves; wave w owns queries qb+w*16 .. +15.
__launch_bounds__(256)
__global__ void attn_flash_kernel(const unsigned short* __restrict__ aqkv,
                                  const float* __restrict__ qk_scale,
                                  const float* __restrict__ qk_offset,
                                  float* __restrict__ pre)
{
    const int qb = blockIdx.x * 64;
    const int head = blockIdx.y;
    const int tid = threadIdx.x, lane = tid & 63, w = tid >> 6;
    const int q0w = qb + w*16;
    const int fr = lane & 15, g4 = lane >> 4;   // frag row/col + k-group

    __shared__ __align__(16) float qs_[AHD], qo_[AHD], ks_[AHD], ko_[AHD];
    __shared__ __align__(16) short Ks[32][136];       // [kv][c] scaled K, bf16
    __shared__ __align__(16) short VsT[AHD][40];      // [c][kv] V transposed
    __shared__ __align__(16) short Pl[4][16][40];     // per-wave P tile

    // stage per-head scale/offset (qk_scale[ch][2] = {q,k})
    if (tid < AHD) {
        float2 s2 = ((const float2*)qk_scale)[head*AHD + tid];
        float2 o2 = ((const float2*)qk_offset)[head*AHD + tid];
        qs_[tid] = s2.x; ks_[tid] = s2.y;
        qo_[tid] = o2.x; ko_[tid] = o2.y;
    }
    __syncthreads();

    // Q fragments (A-layout: row=fr (query), k=g4*8+j), scaled, bf16
    bfrag a_q[4];
    {
        const unsigned short* qrow = aqkv + (size_t)(q0w + fr)*QKV3 + head*AHD;
        #pragma unroll
        for (int cc = 0; cc < 4; ++cc) {
            int c = cc*32 + g4*8;
            uint4 u = *(const uint4*)(qrow + c);
            unsigned int uw[4] = {u.x,u.y,u.z,u.w};
            bfrag f;
            #pragma unroll
            for (int t = 0; t < 4; ++t) {
                float lo = bf2f(uw[t] & 0xffff)*qs_[c+2*t]   + qo_[c+2*t];
                float hi = bf2f(uw[t] >> 16)   *qs_[c+2*t+1] + qo_[c+2*t+1];
                f[2*t]   = (short)f2bf(lo);
                f[2*t+1] = (short)f2bf(hi);
            }
            a_q[cc] = f;
        }
    }

    const int kv_start = (qb >= WIN) ? (qb - WIN) : 0;
    const int ntiles = (qb + 64 - kv_start) >> 5;

    float m_r[4], l_r[4];
    #pragma unroll
    for (int r = 0; r < 4; ++r) { m_r[r] = -1e30f; l_r[r] = 0.f; }
    f32x4 acc_o[8];
    #pragma unroll
    for (int dt = 0; dt < 8; ++dt) acc_o[dt] = f32x4{0.f,0.f,0.f,0.f};

    for (int t = 0; t < ntiles; ++t) {
        const int kv0 = kv_start + t*32;
        __syncthreads();   // previous iteration's LDS reads done
        {   // stage K (scaled) and V^T
            int kvr = tid >> 3, c0 = (tid & 7) * 16;
            const unsigned short* krow = aqkv + (size_t)(kv0 + kvr)*QKV3 + DIM_ + head*AHD + c0;
            uint4 u0 = *(const uint4*)krow, u1 = *(const uint4*)(krow + 8);
            unsigned int uw[8] = {u0.x,u0.y,u0.z,u0.w,u1.x,u1.y,u1.z,u1.w};
            unsigned int pk[8];
            #pragma unroll
            for (int tt = 0; tt < 8; ++tt) {
                int c = c0 + 2*tt;
                float lo = bf2f(uw[tt] & 0xffff)*ks_[c]   + ko_[c];
                float hi = bf2f(uw[tt] >> 16)   *ks_[c+1] + ko_[c+1];
                pk[tt] = (unsigned)f2bf(lo) | ((unsigned)f2bf(hi) << 16);
            }
            *(uint4*)&Ks[kvr][c0]     = make_uint4(pk[0],pk[1],pk[2],pk[3]);
            *(uint4*)&Ks[kvr][c0 + 8] = make_uint4(pk[4],pk[5],pk[6],pk[7]);
            const unsigned short* vrow = aqkv + (size_t)(kv0 + kvr)*QKV3 + 2*DIM_ + head*AHD + c0;
            uint4 v0 = *(const uint4*)vrow, v1 = *(const uint4*)(vrow + 8);
            unsigned int vw[8] = {v0.x,v0.y,v0.z,v0.w,v1.x,v1.y,v1.z,v1.w};
            #pragma unroll
            for (int tt = 0; tt < 8; ++tt) {
                VsT[c0 + 2*tt    ][kvr] = (short)(vw[tt] & 0xffff);
                VsT[c0 + 2*tt + 1][kvr] = (short)(vw[tt] >> 16);
            }
        }
        __syncthreads();

        // S = Q K^T  (two 16-key sub-tiles)
        f32x4 acc_s[2];
        acc_s[0] = f32x4{0.f,0.f,0.f,0.f};
        acc_s[1] = f32x4{0.f,0.f,0.f,0.f};
        #pragma unroll
        for (int kt = 0; kt < 2; ++kt) {
            #pragma unroll
            for (int cc = 0; cc < 4; ++cc) {
                bfrag b_k = *(const bfrag*)&Ks[kt*16 + fr][cc*32 + g4*8];
                acc_s[kt] = __builtin_amdgcn_mfma_f32_16x16x32_bf16(a_q[cc], b_k, acc_s[kt], 0, 0, 0);
            }
        }

        // masked online softmax (C-layout: q = g4*4+r, k = kt*16+fr)
        float p_v[2][4];
        float rm[4];
        #pragma unroll
        for (int r = 0; r < 4; ++r) {
            int q_g = q0w + g4*4 + r;
            float best = -1e30f;
            #pragma unroll
            for (int kt = 0; kt < 2; ++kt) {
                int k_g = kv0 + kt*16 + fr;
                float s = acc_s[kt][r] * 0.088388347648318447f;
                bool valid = (k_g <= q_g) && (k_g + WIN >= q_g);
                p_v[kt][r] = valid ? s : -1e30f;
                best = fmaxf(best, p_v[kt][r]);
            }
            rm[r] = best;
        }
        #pragma unroll
        for (int r = 0; r < 4; ++r) {
            #pragma unroll
            for (int msk = 1; msk < 16; msk <<= 1)
                rm[r] = fmaxf(rm[r], __shfl_xor(rm[r], msk, 64));
        }
        float corr[4], rs[4];
        #pragma unroll
        for (int r = 0; r < 4; ++r) {
            float mn = fmaxf(m_r[r], rm[r]);
            corr[r] = expf(m_r[r] - mn);          // (-1e30)-(-1e30)=0 -> 1
            m_r[r] = mn;
            float loc = 0.f;
            #pragma unroll
            for (int kt = 0; kt < 2; ++kt) {
                float p = (p_v[kt][r] > -1e29f) ? expf(p_v[kt][r] - mn) : 0.f;
                p_v[kt][r] = p;
                loc += p;
            }
            rs[r] = loc;
        }
        #pragma unroll
        for (int r = 0; r < 4; ++r) {
            #pragma unroll
            for (int msk = 1; msk < 16; msk <<= 1)
                rs[r] += __shfl_xor(rs[r], msk, 64);
            l_r[r] = l_r[r]*corr[r] + rs[r];
        }
        #pragma unroll
        for (int dt = 0; dt < 8; ++dt) {
            #pragma unroll
            for (int r = 0; r < 4; ++r) acc_o[dt][r] *= corr[r];
        }

        // P -> per-wave LDS, re-fragment as PV A-operand
        #pragma unroll
        for (int kt = 0; kt < 2; ++kt)
            #pragma unroll
            for (int r = 0; r < 4; ++r)
                Pl[w][g4*4 + r][kt*16 + fr] = (short)f2bf(p_v[kt][r]);
        __syncthreads();

        bfrag a_p = *(const bfrag*)&Pl[w][fr][g4*8];
        #pragma unroll
        for (int dt = 0; dt < 8; ++dt) {
            bfrag b_v = *(const bfrag*)&VsT[dt*16 + fr][g4*8];
            acc_o[dt] = __builtin_amdgcn_mfma_f32_16x16x32_bf16(a_p, b_v, acc_o[dt], 0, 0, 0);
        }
    }

    // epilogue: O = acc/l into PRE
    #pragma unroll
    for (int dt = 0; dt < 8; ++dt) {
        #pragma unroll
        for (int r = 0; r < 4; ++r) {
            int q_g = q0w + g4*4 + r;
            float inv = 1.f / l_r[r];
            pre[(size_t)q_g*DIM_ + head*AHD + dt*16 + fr] += acc_o[dt][r] * inv;
        }
    }
}

// ---------------- host ----------------
extern "C" void kernel_launch(void* const* d_in, const int* in_sizes, int n_in,
                              void* d_out, int out_size, void* d_ws, size_t ws_size,
                              hipStream_t stream)
{
    (void)in_sizes; (void)n_in; (void)out_size; (void)ws_size;
    const float* x        = (const float*)d_in[0];
    const float* Wqkv     = (const float*)d_in[1];
    const float* Wlr      = (const float*)d_in[2];
    const float* Wm       = (const float*)d_in[3];
    const float* bm       = (const float*)d_in[4];
    const float* Wsc      = (const float*)d_in[5];
    const float* bsc      = (const float*)d_in[6];
    const float* Wo       = (const float*)d_in[7];
    const float* w0       = (const float*)d_in[8];
    const float* w1       = (const float*)d_in[9];
    const float* w2       = (const float*)d_in[10];
    const float* o_norm_g = (const float*)d_in[11];
    const float* qk_scale = (const float*)d_in[12];
    const float* qk_offset= (const float*)d_in[13];
    float* out = (float*)d_out;

    const long HDHD = (long)HD*HD;
    const long CH_HD = (long)CHUNK_*HD;

    char* pc = (char*)d_ws;
    unsigned short* AQKV = (unsigned short*)pc; pc += (size_t)L_SEQ*QKV3*sizeof(unsigned short);
    float* PRE  = (float*)pc; pc += (size_t)L_SEQ*DIM_*sizeof(float);
    float* KC   = (float*)pc; pc += (size_t)NH_*CH_HD*sizeof(float);
    float* VC   = (float*)pc; pc += (size_t)NH_*CH_HD*sizeof(float);
    float* A1   = (float*)pc; pc += (size_t)NH_*CH_HD*sizeof(float);
    float* B1   = (float*)pc; pc += (size_t)NH_*CH_HD*sizeof(float);
    float* D1   = (float*)pc; pc += (size_t)NH_*CH_HD*sizeof(float);
    float* QCC1 = (float*)pc; pc += (size_t)NH_*CH_HD*sizeof(float);
    float* WST  = (float*)pc; pc += (size_t)3*NH_*HDHD*sizeof(float);
    float* MST  = (float*)pc; pc += (size_t)3*NH_*HDHD*sizeof(float);
    float* XB   = (float*)pc; pc += (size_t)3*NH_*HDHD*sizeof(float);
    float* AB   = (float*)pc; pc += (size_t)3*NH_*HDHD*sizeof(float);
    float* TB   = (float*)pc; pc += (size_t)3*NH_*HDHD*sizeof(float);
    float* NV   = (float*)pc; pc += (size_t)3*NH_*HD*sizeof(float);
    float* LR0  = (float*)pc; pc += (size_t)NH_*L_SEQ*sizeof(float);
    float* LR1  = (float*)pc; pc += (size_t)NH_*L_SEQ*sizeof(float);
    float* LR2  = (float*)pc; pc += (size_t)NH_*L_SEQ*sizeof(float);
    float* MOMB = (float*)pc; pc += (size_t)NH_*L_SEQ*sizeof(float);
    float* SCB  = (float*)pc; pc += (size_t)NH_*L_SEQ*sizeof(float);
    float* MMB  = (float*)pc; pc += (size_t)NC_*NH_*sizeof(float);
    float* FRO  = (float*)pc; pc += 16*sizeof(float);

    // 1. attn_qkv = x @ Wqkv (MFMA, bf16 store)
    launch_mfma<0,0,false,true>(stream, x, Wqkv, AQKV, L_SEQ, QKV3, DIM_, QKV3, 0,0,0, 1);

    // 2. lr / mom / scale skinny projections
    skinny_kernel<<<L_SEQ,256,0,stream>>>(x, Wlr, Wm, bm, Wsc, bsc, LR0,LR1,LR2, MOMB, SCB);
    mm_mean_kernel<<<NC_*NH_,256,0,stream>>>(MOMB, MMB);

    // 3. init TTT states
    size_t wbytes = (size_t)NH_*HDHD*sizeof(float);
    hipMemcpyAsync(WST,              w0, wbytes, hipMemcpyDeviceToDevice, stream);
    hipMemcpyAsync(WST + NH_*HDHD,   w1, wbytes, hipMemcpyDeviceToDevice, stream);
    hipMemcpyAsync(WST + 2*NH_*HDHD, w2, wbytes, hipMemcpyDeviceToDevice, stream);
    hipMemsetAsync(MST, 0, 3*wbytes, stream);
    norm_rows_kernel<<<3*NH_*HD,64,0,stream>>>(WST, NV);

    const float nsA[5] = {4.0848f, 3.9505f, 3.7418f, 2.8769f, 2.8366f};
    const float nsB[5] = {-6.8946f,-6.3029f,-5.5913f,-3.1427f,-3.0525f};
    const float nsC[5] = {2.927f,  2.6377f, 2.3037f, 1.2046f, 1.2012f};

    // 4. sequential chunk scan
    for (int ci = 0; ci < NC_; ++ci) {
        qkv_prep_kernel<<<NH_*CHUNK_,64,0,stream>>>(AQKV, QCC1, KC, VC, ci);
        float* W0s = WST;
        float* W1s = WST + NH_*HDHD;
        float* W2s = WST + 2*NH_*HDHD;
        launch_mfma<0,1,false,false>(stream, QCC1, W0s, A1, CHUNK_, HD, HD, HD, CH_HD, HDHD, CH_HD, NH_);
        launch_mfma<0,1,false,false>(stream, QCC1, W2s, B1, CHUNK_, HD, HD, HD, CH_HD, HDHD, CH_HD, NH_);
        ew_gh_kernel<<<4096,256,0,stream>>>(A1, B1, D1, (long)NH_*CH_HD);
        launch_mfma<0,1,false,false>(stream, D1, W1s, PRE + (size_t)ci*CHUNK_*DIM_,
                                     CHUNK_, HD, HD, DIM_, CH_HD, HDHD, HD, NH_);
        launch_mfma<0,1,false,false>(stream, KC, W0s, A1, CHUNK_, HD, HD, HD, CH_HD, HDHD, CH_HD, NH_);
        launch_mfma<0,1,false,false>(stream, KC, W2s, B1, CHUNK_, HD, HD, HD, CH_HD, HDHD, CH_HD, NH_);
        launch_mfma<0,0,false,false>(stream, VC, W1s, QCC1, CHUNK_, HD, HD, HD, CH_HD, HDHD, CH_HD, NH_);
        ew_bwd_kernel<<<4096,256,0,stream>>>(A1, B1, QCC1, D1, (long)NH_*CH_HD);
        launch_mfma<1,0,true,false>(stream, A1, KC, XB,              HD, HD, CHUNK_, HD, CH_HD, CH_HD, HDHD, NH_, LR0 + ci*CHUNK_, (long)L_SEQ);
        launch_mfma<1,0,true,false>(stream, VC, D1, XB + NH_*HDHD,   HD, HD, CHUNK_, HD, CH_HD, CH_HD, HDHD, NH_, LR1 + ci*CHUNK_, (long)L_SEQ);
        launch_mfma<1,0,true,false>(stream, B1, KC, XB + 2*NH_*HDHD, HD, HD, CHUNK_, HD, CH_HD, CH_HD, HDHD, NH_, LR2 + ci*CHUNK_, (long)L_SEQ);
        momentum_kernel<<<4096,256,0,stream>>>(XB, MST, MMB + ci*NH_, 3L*NH_*HDHD);
        frob_kernel<<<12,256,0,stream>>>(XB, FRO);
        scalex_kernel<<<4096,256,0,stream>>>(XB, FRO, 3L*NH_*HDHD);
        float* Xc = XB; float* Tc = TB;
        for (int it = 0; it < 5; ++it) {
            gemm_nt_f32(stream, Xc, Xc, AB, HD,HD,HD, HDHD,HDHD,HDHD, 12);
            gemm_nn_f32(stream, AB, AB, Tc, HD,HD,HD, HDHD,HDHD,HDHD, 12);
            ns_ew_kernel<<<4096,256,0,stream>>>(AB, Tc, nsB[it], nsC[it], 3L*NH_*HDHD);
            gemm_nn_add_f32(stream, AB, Xc, Tc, HD,HD,HD, HDHD,HDHD,HDHD, 12, Xc, HDHD, nsA[it]);
            float* t_ = Xc; Xc = Tc; Tc = t_;
        }
        renorm_kernel<<<3*NH_*HD,64,0,stream>>>(WST, Xc, NV);
    }

    // 5. TTT post: in-place rms-norm * g * scale on PRE
    ttt_post_kernel<<<NH_*L_SEQ,64,0,stream>>>(PRE, SCB, o_norm_g);

    // 6. MFMA flash sliding-window attention adds into PRE
    attn_flash_kernel<<<dim3(L_SEQ/64, NAH_),256,0,stream>>>(AQKV, qk_scale, qk_offset, PRE);

    // 7. final projection (MFMA, fp32 out)
    launch_mfma<0,0,false,false>(stream, PRE, Wo, out, L_SEQ, DIM_, DIM_, DIM_, 0,0,0, 1);
}